// Round 3
// baseline (2921.054 us; speedup 1.0000x reference)
//
#include <hip/hip_runtime.h>
#include <math.h>

#define T_ 256
#define B_ 32
#define E_ 256
#define HD_ 256
#define NG_ 1024
#define K_ 12
#define START_ 10
#define STOP_ 11
#define NEG_ -10000.0f

__device__ __forceinline__ float sigf(float x) { return 1.0f / (1.0f + expf(-x)); }

// ---------- token gather (bwd dir reversed within each sequence length) ----------
__global__ void tok_gather(const int* __restrict__ sent, const int* __restrict__ lens,
                           int* __restrict__ tokA) {
    int e = blockIdx.x * 256 + threadIdx.x;      // 0..16383 = [dir][t*32+b]
    int dir = e >> 13, m = e & 8191, t = m >> 5, b = m & 31;
    int len = lens[b];
    int tt = dir ? (t < len ? len - 1 - t : t) : t;
    tokA[e] = sent[b * T_ + tt];
}

// ---------- Whh^T into [dir][k][u*4+gate] (unit-major gate packing) ----------
__global__ void whh_tr(const float* __restrict__ Wf, const float* __restrict__ Wb,
                       float* __restrict__ WT) {
    int dir = blockIdx.x >> 8, k = blockIdx.x & 255, u = threadIdx.x;
    const float* W = dir ? Wb : Wf;
    float4 v;
    v.x = W[(0 * HD_ + u) * HD_ + k];   // i
    v.y = W[(1 * HD_ + u) * HD_ + k];   // f
    v.z = W[(2 * HD_ + u) * HD_ + k];   // g
    v.w = W[(3 * HD_ + u) * HD_ + k];   // o
    ((float4*)(WT + ((size_t)dir * 256 + k) * NG_))[u] = v;
}

// ---------- zero the sync flags (ws is poisoned 0xAA before every launch) ----------
__global__ void init_flags(int* __restrict__ flags) {
    flags[threadIdx.x] = 0;   // 128 flags
}

// ---------- fused embedding-gather + input GEMM: G[dir][t*32+b][u*4+g] = x@Wih^T + bih + bhh ----------
__global__ __launch_bounds__(256) void in_gemm(
    const float* __restrict__ emb, const int* __restrict__ tokA,
    const float* __restrict__ Wih_f, const float* __restrict__ Wih_b,
    const float* __restrict__ bih_f, const float* __restrict__ bhh_f,
    const float* __restrict__ bih_b, const float* __restrict__ bhh_b,
    float* __restrict__ G) {
    const int dir = blockIdx.z;
    const int n0 = blockIdx.x * 128, m0 = blockIdx.y * 128;
    const float* Wih = dir ? Wih_b : Wih_f;
    const float* bihp = dir ? bih_b : bih_f;
    const float* bhhp = dir ? bhh_b : bhh_f;
    __shared__ float As[8][128];
    __shared__ float Bs[8][128];
    const int tid = threadIdx.x;
    const int rs = tid >> 1, kc = (tid & 1) * 4;
    const int tok = tokA[dir * 8192 + m0 + rs];
    const float* arow = emb + (size_t)tok * E_;
    const int np = n0 + rs;
    const int wrow = ((np & 3) << 8) | (np >> 2);     // permuted col n'=u*4+g -> Wih row g*256+u
    const float* brow = Wih + (size_t)wrow * E_;
    const int ty = tid >> 4, tx = tid & 15;

    float acc[8][8];
#pragma unroll
    for (int i = 0; i < 8; ++i)
#pragma unroll
        for (int j = 0; j < 8; ++j) acc[i][j] = 0.f;

    for (int k0 = 0; k0 < E_; k0 += 8) {
        float4 av = *(const float4*)(arow + k0 + kc);
        float4 bv = *(const float4*)(brow + k0 + kc);
        __syncthreads();
        As[kc + 0][rs] = av.x; As[kc + 1][rs] = av.y; As[kc + 2][rs] = av.z; As[kc + 3][rs] = av.w;
        Bs[kc + 0][rs] = bv.x; Bs[kc + 1][rs] = bv.y; Bs[kc + 2][rs] = bv.z; Bs[kc + 3][rs] = bv.w;
        __syncthreads();
#pragma unroll
        for (int k = 0; k < 8; ++k) {
            float4 a0 = *(const float4*)&As[k][ty * 8];
            float4 a1 = *(const float4*)&As[k][ty * 8 + 4];
            float4 b0 = *(const float4*)&Bs[k][tx * 8];
            float4 b1 = *(const float4*)&Bs[k][tx * 8 + 4];
            float af8[8] = {a0.x, a0.y, a0.z, a0.w, a1.x, a1.y, a1.z, a1.w};
            float bf8[8] = {b0.x, b0.y, b0.z, b0.w, b1.x, b1.y, b1.z, b1.w};
#pragma unroll
            for (int i = 0; i < 8; ++i)
#pragma unroll
                for (int j = 0; j < 8; ++j) acc[i][j] += af8[i] * bf8[j];
        }
    }
    float bias[8];
#pragma unroll
    for (int j = 0; j < 8; ++j) {
        int nn = n0 + tx * 8 + j;
        int wr = ((nn & 3) << 8) | (nn >> 2);
        bias[j] = bihp[wr] + bhhp[wr];
    }
#pragma unroll
    for (int i = 0; i < 8; ++i) {
        int m = m0 + ty * 8 + i;
        float* gp = G + ((size_t)dir * 8192 + m) * NG_ + n0 + tx * 8;
        float4 o0 = {acc[i][0] + bias[0], acc[i][1] + bias[1], acc[i][2] + bias[2], acc[i][3] + bias[3]};
        float4 o1 = {acc[i][4] + bias[4], acc[i][5] + bias[5], acc[i][6] + bias[6], acc[i][7] + bias[7]};
        *(float4*)gp = o0;
        *(float4*)(gp + 4) = o1;
    }
}

// ---------- recurrence v3: WG = (dir, unit-tile of 16); each WG interleaves the 4
// batch-groups of its dir per step so the sc1/L3 exchange latency of one group is
// hidden behind the compute of the other three. 32 WGs x 256 threads. ----------
__global__ __launch_bounds__(256) void lstm_rec3(
    const float* __restrict__ WhhT, const float* __restrict__ G,
    const float* __restrict__ h0, const float* __restrict__ c0,
    const int* __restrict__ lens, float* __restrict__ hout,
    float* __restrict__ hex, int* __restrict__ flags) {
    const int dir = blockIdx.x >> 4, ut = blockIdx.x & 15;
    const int tid = threadIdx.x;
    const int u = tid & 15;                      // unit within tile (16)
    const int ks = tid >> 4;                     // k-slice 0..15 (16 k each)
    const int fb = tid >> 4;                     // (tid<128) batch within group

    __shared__ float hs[2048];                   // h(t-1): [k][b], b fast (8 KB)
    __shared__ float red[4 * 16 * 36];           // [wv][u][b*4+g] pitch 36 (9 KB)

    const int gu = ut * 16 + u;                  // global unit column in WhhT

    int Tg[4];
#pragma unroll
    for (int g = 0; g < 4; ++g) Tg[g] = lens[g * 8];   // sorted desc -> max of group
    const int Tmax = Tg[0];

    float cst[4]; int lenb[4];
    if (tid < 128) {
#pragma unroll
        for (int g = 0; g < 4; ++g) {
            cst[g] = c0[(dir * B_ + g * 8 + fb) * HD_ + gu];
            lenb[g] = lens[g * 8 + fb];
        }
    }

    const float4* WT4 = (const float4*)(WhhT + (size_t)dir * 256 * NG_);
    const float* Gd = G + (size_t)dir * 8192 * NG_;

    for (int t = 0; t < Tmax; ++t) {
#pragma unroll 1
        for (int g = 0; g < 4; ++g) {
            if (t >= Tg[g]) continue;
            float* hexg = hex + (size_t)(dir * 4 + g) * 2 * 2048;
            const int fbase = (dir * 4 + g) * 16;

            // ---- stage h(t-1) for this group into LDS ----
            if (t == 0) {
                int k = tid;                         // 0..255
#pragma unroll
                for (int b = 0; b < 8; ++b)
                    hs[k * 8 + b] = h0[(dir * B_ + g * 8 + b) * HD_ + k];
            } else {
                if (tid < 16) {
                    int it = 0;
                    while (__hip_atomic_load(&flags[fbase + tid], __ATOMIC_RELAXED,
                                             __HIP_MEMORY_SCOPE_AGENT) < t) {
                        __builtin_amdgcn_s_sleep(1);
                        if (++it > (1 << 24)) break;     // bail -> visible failure, not hang
                    }
                }
                __syncthreads();
                const float* src = hexg + ((t - 1) & 1) * 2048;
                int i = tid * 8;
#pragma unroll
                for (int j = 0; j < 8; ++j)
                    hs[i + j] = __hip_atomic_load(&src[i + j], __ATOMIC_RELAXED,
                                                  __HIP_MEMORY_SCOPE_AGENT);
            }
            __syncthreads();

            // ---- recurrent GEMM slice: acc[b] (4 gates) over this thread's 16 k ----
            float4 acc[8];
#pragma unroll
            for (int b = 0; b < 8; ++b) acc[b] = make_float4(0.f, 0.f, 0.f, 0.f);
            const float4* hs4 = (const float4*)hs;
            const int kbase = ks * 16;
#pragma unroll 4
            for (int j = 0; j < 16; ++j) {
                int k = kbase + j;
                float4 w = WT4[(k << 8) + gu];        // W slice streamed from L2
                float4 hA = hs4[k * 2 + 0];           // h[k][b0..3] broadcast
                float4 hB = hs4[k * 2 + 1];           // h[k][b4..7] broadcast
                acc[0].x += w.x * hA.x; acc[0].y += w.y * hA.x; acc[0].z += w.z * hA.x; acc[0].w += w.w * hA.x;
                acc[1].x += w.x * hA.y; acc[1].y += w.y * hA.y; acc[1].z += w.z * hA.y; acc[1].w += w.w * hA.y;
                acc[2].x += w.x * hA.z; acc[2].y += w.y * hA.z; acc[2].z += w.z * hA.z; acc[2].w += w.w * hA.z;
                acc[3].x += w.x * hA.w; acc[3].y += w.y * hA.w; acc[3].z += w.z * hA.w; acc[3].w += w.w * hA.w;
                acc[4].x += w.x * hB.x; acc[4].y += w.y * hB.x; acc[4].z += w.z * hB.x; acc[4].w += w.w * hB.x;
                acc[5].x += w.x * hB.y; acc[5].y += w.y * hB.y; acc[5].z += w.z * hB.y; acc[5].w += w.w * hB.y;
                acc[6].x += w.x * hB.z; acc[6].y += w.y * hB.z; acc[6].z += w.z * hB.z; acc[6].w += w.w * hB.z;
                acc[7].x += w.x * hB.w; acc[7].y += w.y * hB.w; acc[7].z += w.z * hB.w; acc[7].w += w.w * hB.w;
            }

            // G pre-activation (includes both biases), issue early
            float4 g4 = make_float4(0.f, 0.f, 0.f, 0.f);
            if (tid < 128)
                g4 = ((const float4*)(Gd + ((size_t)t * B_ + g * 8 + fb) * NG_))[gu];

            // ---- reduce the 16 k-slices: 2 shfl rounds (in-wave), then LDS tree ----
#pragma unroll
            for (int b = 0; b < 8; ++b) {
                acc[b].x += __shfl_xor(acc[b].x, 16);
                acc[b].y += __shfl_xor(acc[b].y, 16);
                acc[b].z += __shfl_xor(acc[b].z, 16);
                acc[b].w += __shfl_xor(acc[b].w, 16);
                acc[b].x += __shfl_xor(acc[b].x, 32);
                acc[b].y += __shfl_xor(acc[b].y, 32);
                acc[b].z += __shfl_xor(acc[b].z, 32);
                acc[b].w += __shfl_xor(acc[b].w, 32);
            }
            int wv = tid >> 6;                        // wave 0..3
            if ((tid & 48) == 0) {
                float4* r4 = (float4*)&red[(wv * 16 + u) * 36];
#pragma unroll
                for (int b = 0; b < 8; ++b) r4[b] = acc[b];
            }
            __syncthreads();

            if (tid < 128) {
                float si = g4.x, sf = g4.y, sg = g4.z, so = g4.w;
#pragma unroll
                for (int w = 0; w < 4; ++w) {
                    float4 p = *(const float4*)&red[(w * 16 + u) * 36 + fb * 4];
                    si += p.x; sf += p.y; sg += p.z; so += p.w;
                }
                float c = sigf(sf) * cst[g] + sigf(si) * tanhf(sg);
                cst[g] = c;
                float h = sigf(so) * tanhf(c);
                int lb = lenb[g];
                int tt = dir ? (t < lb ? lb - 1 - t : t) : t;
                hout[(((size_t)(dir * B_ + g * 8 + fb)) * T_ + tt) * HD_ + gu] = h;
                __hip_atomic_store(&hexg[(t & 1) * 2048 + gu * 8 + fb], h,
                                   __ATOMIC_RELAXED, __HIP_MEMORY_SCOPE_AGENT);
            }
            __syncthreads();   // drains every wave's vmcnt -> hex stores are L3-visible
            if (tid == 0)
                __hip_atomic_store(&flags[fbase + ut], t + 1,
                                   __ATOMIC_RELAXED, __HIP_MEMORY_SCOPE_AGENT);
        }
    }
}

// ---------- features: feats[b*T+t][k] = hcat . W_out[k] + b_out[k] ----------
__global__ void feat_k(const float* __restrict__ hout, const float* __restrict__ Wout,
                       const float* __restrict__ bout, float* __restrict__ feats) {
    int tid = threadIdx.x;                 // 192 = 16 pos x 12 tags
    int pl = tid / 12, k = tid % 12;
    int p = blockIdx.x * 16 + pl;          // p = b*256 + t
    const float4* hf = (const float4*)(hout + (size_t)p * HD_);
    const float4* hb = (const float4*)(hout + (size_t)(B_ * T_ + p) * HD_);
    const float4* w0 = (const float4*)(Wout + (size_t)k * 512);
    const float4* w1 = (const float4*)(Wout + (size_t)k * 512 + 256);
    float acc = bout[k];
#pragma unroll 4
    for (int j = 0; j < 64; ++j) {
        float4 h4 = hf[j], v4 = w0[j];
        acc += h4.x * v4.x + h4.y * v4.y + h4.z * v4.z + h4.w * v4.w;
    }
#pragma unroll 4
    for (int j = 0; j < 64; ++j) {
        float4 h4 = hb[j], v4 = w1[j];
        acc += h4.x * v4.x + h4.y * v4.y + h4.z * v4.z + h4.w * v4.w;
    }
    feats[(size_t)p * K_ + k] = acc;
}

// ---------- Viterbi + backtrace: single block, bp nibble-packed in LDS ----------
__global__ __launch_bounds__(512) void viterbi_k(
    const float* __restrict__ feats, const float* __restrict__ trans,
    const int* __restrict__ lens, float* __restrict__ out) {
    __shared__ float fv[2][B_][16];
    __shared__ float tl[K_][16];
    __shared__ unsigned char bp[T_][B_][6];    // 4-bit backpointers, 48KB
    __shared__ int best_last[B_];
    int tid = threadIdx.x;
    int b = tid >> 4, lane = tid & 15;
    if (tid < K_ * K_) tl[tid / 12][tid % 12] = trans[tid];
    if (lane < K_) fv[0][b][lane] = (lane == START_) ? 0.f : NEG_;
    __syncthreads();
    int len = lens[b];
    int pp = 0;
    for (int t = 0; t < T_; ++t) {
        if (lane < K_) {
            float best = fv[pp][b][0] + tl[lane][0];
            int argp = 0;
#pragma unroll
            for (int p = 1; p < K_; ++p) {
                float v = fv[pp][b][p] + tl[lane][p];
                if (v > best) { best = v; argp = p; }   // strict > = first-max (matches jnp.argmax)
            }
            float nb = best + feats[((size_t)b * T_ + t) * K_ + lane];
            fv[pp ^ 1][b][lane] = (t < len) ? nb : fv[pp][b][lane];
            int other = __shfl_xor(argp, 1);
            if ((lane & 1) == 0) bp[t][b][lane >> 1] = (unsigned char)(argp | (other << 4));
        }
        __syncthreads();
        pp ^= 1;
    }
    if (lane == 0) {
        float best = fv[pp][b][0] + tl[STOP_][0];
        int bl = 0;
#pragma unroll
        for (int p = 1; p < K_; ++p) {
            float v = fv[pp][b][p] + tl[STOP_][p];
            if (v > best) { best = v; bl = p; }
        }
        out[b] = best;
        best_last[b] = bl;
    }
    __syncthreads();
    if (lane == 0) {
        int tag = best_last[b];
        for (int t = T_ - 1; t >= 0; --t) {
            int m = (t < len);
            out[B_ + b * T_ + t] = (float)(m ? tag : -1);
            if (m) tag = (bp[t][b][tag >> 1] >> ((tag & 1) * 4)) & 15;
        }
    }
}

extern "C" void kernel_launch(void* const* d_in, const int* in_sizes, int n_in,
                              void* d_out, int out_size, void* d_ws, size_t ws_size,
                              hipStream_t stream) {
    const int*   sent  = (const int*)d_in[0];
    const int*   lens  = (const int*)d_in[1];
    const float* emb   = (const float*)d_in[2];
    const float* Wih_f = (const float*)d_in[3];
    const float* Whh_f = (const float*)d_in[4];
    const float* bih_f = (const float*)d_in[5];
    const float* bhh_f = (const float*)d_in[6];
    const float* Wih_b = (const float*)d_in[7];
    const float* Whh_b = (const float*)d_in[8];
    const float* bih_b = (const float*)d_in[9];
    const float* bhh_b = (const float*)d_in[10];
    const float* h0    = (const float*)d_in[11];
    const float* c0    = (const float*)d_in[12];
    const float* Wout  = (const float*)d_in[13];
    const float* bout  = (const float*)d_in[14];
    const float* trans = (const float*)d_in[15];
    float* out = (float*)d_out;

    char* ws = (char*)d_ws;
    int*   tokA  = (int*)ws;                                            // 64 KB
    float* WhhT  = (float*)(ws + 65536);                                // 2 MB
    float* G     = (float*)(ws + 65536 + 2097152);                      // 67.1 MB
    float* hout  = (float*)(ws + 65536 + 2097152 + 67108864);           // 16.8 MB
    float* feats = (float*)(ws + 65536 + 2097152 + 67108864 + 16777216);// 0.39 MB
    float* hex   = (float*)(ws + 86441984);                             // 128 KB h-exchange
    int*   flags = (int*)(ws + 86441984 + 131072);                      // 512 B

    tok_gather<<<64, 256, 0, stream>>>(sent, lens, tokA);
    whh_tr<<<512, 256, 0, stream>>>(Whh_f, Whh_b, WhhT);
    init_flags<<<1, 128, 0, stream>>>(flags);
    in_gemm<<<dim3(8, 64, 2), 256, 0, stream>>>(emb, tokA, Wih_f, Wih_b,
                                                bih_f, bhh_f, bih_b, bhh_b, G);
    lstm_rec3<<<32, 256, 0, stream>>>(WhhT, G, h0, c0, lens, hout, hex, flags);
    feat_k<<<512, 192, 0, stream>>>(hout, Wout, bout, feats);
    viterbi_k<<<1, 512, 0, stream>>>(feats, trans, lens, out);
}

// Round 4
// 1347.491 us; speedup vs baseline: 2.1678x; 2.1678x over previous
//
#include <hip/hip_runtime.h>
#include <math.h>

#define T_ 256
#define B_ 32
#define E_ 256
#define HD_ 256
#define NG_ 1024
#define K_ 12
#define START_ 10
#define STOP_ 11
#define NEG_ -10000.0f

__device__ __forceinline__ float sigf(float x) { return 1.0f / (1.0f + expf(-x)); }

// ---------- token gather (bwd dir reversed within each sequence length) ----------
__global__ void tok_gather(const int* __restrict__ sent, const int* __restrict__ lens,
                           int* __restrict__ tokA) {
    int e = blockIdx.x * 256 + threadIdx.x;      // 0..16383 = [dir][t*32+b]
    int dir = e >> 13, m = e & 8191, t = m >> 5, b = m & 31;
    int len = lens[b];
    int tt = dir ? (t < len ? len - 1 - t : t) : t;
    tokA[e] = sent[b * T_ + tt];
}

// ---------- Whh^T into [dir][k][u*4+gate] (unit-major gate packing) ----------
__global__ void whh_tr(const float* __restrict__ Wf, const float* __restrict__ Wb,
                       float* __restrict__ WT) {
    int dir = blockIdx.x >> 8, k = blockIdx.x & 255, u = threadIdx.x;
    const float* W = dir ? Wb : Wf;
    float4 v;
    v.x = W[(0 * HD_ + u) * HD_ + k];   // i
    v.y = W[(1 * HD_ + u) * HD_ + k];   // f
    v.z = W[(2 * HD_ + u) * HD_ + k];   // g
    v.w = W[(3 * HD_ + u) * HD_ + k];   // o
    ((float4*)(WT + ((size_t)dir * 256 + k) * NG_))[u] = v;
}

// ---------- zero the sync flags (ws is poisoned 0xAA before every launch) ----------
__global__ void init_flags(int* __restrict__ flags) {
    flags[threadIdx.x] = 0;   // 256 ints (64 flags padded x4)
}

// ---------- fused embedding-gather + input GEMM: G[dir][t*32+b][u*4+g] = x@Wih^T + bih + bhh ----------
__global__ __launch_bounds__(256) void in_gemm(
    const float* __restrict__ emb, const int* __restrict__ tokA,
    const float* __restrict__ Wih_f, const float* __restrict__ Wih_b,
    const float* __restrict__ bih_f, const float* __restrict__ bhh_f,
    const float* __restrict__ bih_b, const float* __restrict__ bhh_b,
    float* __restrict__ G) {
    const int dir = blockIdx.z;
    const int n0 = blockIdx.x * 128, m0 = blockIdx.y * 128;
    const float* Wih = dir ? Wih_b : Wih_f;
    const float* bihp = dir ? bih_b : bih_f;
    const float* bhhp = dir ? bhh_b : bhh_f;
    __shared__ float As[8][128];
    __shared__ float Bs[8][128];
    const int tid = threadIdx.x;
    const int rs = tid >> 1, kc = (tid & 1) * 4;
    const int tok = tokA[dir * 8192 + m0 + rs];
    const float* arow = emb + (size_t)tok * E_;
    const int np = n0 + rs;
    const int wrow = ((np & 3) << 8) | (np >> 2);     // permuted col n'=u*4+g -> Wih row g*256+u
    const float* brow = Wih + (size_t)wrow * E_;
    const int ty = tid >> 4, tx = tid & 15;

    float acc[8][8];
#pragma unroll
    for (int i = 0; i < 8; ++i)
#pragma unroll
        for (int j = 0; j < 8; ++j) acc[i][j] = 0.f;

    for (int k0 = 0; k0 < E_; k0 += 8) {
        float4 av = *(const float4*)(arow + k0 + kc);
        float4 bv = *(const float4*)(brow + k0 + kc);
        __syncthreads();
        As[kc + 0][rs] = av.x; As[kc + 1][rs] = av.y; As[kc + 2][rs] = av.z; As[kc + 3][rs] = av.w;
        Bs[kc + 0][rs] = bv.x; Bs[kc + 1][rs] = bv.y; Bs[kc + 2][rs] = bv.z; Bs[kc + 3][rs] = bv.w;
        __syncthreads();
#pragma unroll
        for (int k = 0; k < 8; ++k) {
            float4 a0 = *(const float4*)&As[k][ty * 8];
            float4 a1 = *(const float4*)&As[k][ty * 8 + 4];
            float4 b0 = *(const float4*)&Bs[k][tx * 8];
            float4 b1 = *(const float4*)&Bs[k][tx * 8 + 4];
            float af8[8] = {a0.x, a0.y, a0.z, a0.w, a1.x, a1.y, a1.z, a1.w};
            float bf8[8] = {b0.x, b0.y, b0.z, b0.w, b1.x, b1.y, b1.z, b1.w};
#pragma unroll
            for (int i = 0; i < 8; ++i)
#pragma unroll
                for (int j = 0; j < 8; ++j) acc[i][j] += af8[i] * bf8[j];
        }
    }
    float bias[8];
#pragma unroll
    for (int j = 0; j < 8; ++j) {
        int nn = n0 + tx * 8 + j;
        int wr = ((nn & 3) << 8) | (nn >> 2);
        bias[j] = bihp[wr] + bhhp[wr];
    }
#pragma unroll
    for (int i = 0; i < 8; ++i) {
        int m = m0 + ty * 8 + i;
        float* gp = G + ((size_t)dir * 8192 + m) * NG_ + n0 + tx * 8;
        float4 o0 = {acc[i][0] + bias[0], acc[i][1] + bias[1], acc[i][2] + bias[2], acc[i][3] + bias[3]};
        float4 o1 = {acc[i][4] + bias[4], acc[i][5] + bias[5], acc[i][6] + bias[6], acc[i][7] + bias[7]};
        *(float4*)gp = o0;
        *(float4*)(gp + 4) = o1;
    }
}

// ---------- recurrence v4: v2 grid (64 WGs = dir x 4 bt x 8 ut, 512 thr) with
// W in registers, per-wave peer polling (wave w <-> peer w), hout off critical path.
__global__ __launch_bounds__(512, 2) void lstm_rec4(
    const float* __restrict__ WhhT, const float* __restrict__ G,
    const float* __restrict__ h0, const float* __restrict__ c0,
    const int* __restrict__ lens, float* __restrict__ hout,
    float* __restrict__ hex, int* __restrict__ flags) {
    const int wg = blockIdx.x;                   // dir*32 + bt*8 + ut
    const int dir = wg >> 5, bt = (wg >> 3) & 3, ut = wg & 7;
    const int tid = threadIdx.x;
    const int u = tid & 31;                      // unit within tile
    const int ks = tid >> 5;                     // k-slice 0..15 (16 k each)
    const int fb = tid >> 5;                     // (tid<256) batch within group
    const int wv = tid >> 6;                     // wave 0..7  <-> peer wv
    const int lane = tid & 63;

    __shared__ float hs[2048];                   // h(t-1): [k][b], b fast
    __shared__ float red[256 * 33];              // wave partials, pitch 33

    const int Tmax = lens[bt * 8];               // lens sorted desc -> group max

    float c = 0.f; int len_b = 0;
    if (tid < 256) {
        c = c0[(dir * B_ + bt * 8 + fb) * HD_ + ut * 32 + u];
        len_b = lens[bt * 8 + fb];
    }

    // ---- W slice into registers: 16 float4/thread, loaded once ----
    const float4* WT4 = (const float4*)(WhhT + (size_t)dir * 256 * NG_);
    float4 Wr[16];
#pragma unroll
    for (int j = 0; j < 16; ++j) Wr[j] = WT4[(((ks * 16 + j)) << 8) + ut * 32 + u];

    const float* Gd = G + (size_t)dir * 8192 * NG_;
    float* hexg = hex + (size_t)(dir * 4 + bt) * 2 * 2048;   // [parity][k][b]
    const int fbase = (dir * 4 + bt) * 8;                    // flag group base
    // per-wave hex-read mapping: dword offset within slot = wv*256 + lane*4
    const int roff = wv * 256 + lane * 4;

    for (int t = 0; t < Tmax; ++t) {
        // G pre-activation for this step — issue before the poll so L3 latency hides
        float4 g4 = make_float4(0.f, 0.f, 0.f, 0.f);
        if (tid < 256)
            g4 = ((const float4*)(Gd + ((size_t)t * B_ + bt * 8 + fb) * NG_))[ut * 32 + u];

        if (t == 0) {
            // stage h0 (transposed gather, once)
            const int base = (dir * B_ + bt * 8) * HD_;
            const int rk = wv * 32 + (lane >> 1), b4 = (lane & 1) * 4;
            float4 v;
            v.x = h0[base + (b4 + 0) * HD_ + rk];
            v.y = h0[base + (b4 + 1) * HD_ + rk];
            v.z = h0[base + (b4 + 2) * HD_ + rk];
            v.w = h0[base + (b4 + 3) * HD_ + rk];
            *(float4*)&hs[roff] = v;
        } else {
            // each wave waits only on its own peer (all lanes poll same address)
            int it = 0;
            while (__hip_atomic_load(&flags[(fbase + wv) * 4], __ATOMIC_RELAXED,
                                     __HIP_MEMORY_SCOPE_AGENT) < t) {
                __builtin_amdgcn_s_sleep(1);
                if (++it > (1 << 22)) break;     // bail -> visible failure, not hang
            }
            const float* src = hexg + ((t - 1) & 1) * 2048;
            float a0 = __hip_atomic_load(&src[roff + 0], __ATOMIC_RELAXED, __HIP_MEMORY_SCOPE_AGENT);
            float a1 = __hip_atomic_load(&src[roff + 1], __ATOMIC_RELAXED, __HIP_MEMORY_SCOPE_AGENT);
            float a2 = __hip_atomic_load(&src[roff + 2], __ATOMIC_RELAXED, __HIP_MEMORY_SCOPE_AGENT);
            float a3 = __hip_atomic_load(&src[roff + 3], __ATOMIC_RELAXED, __HIP_MEMORY_SCOPE_AGENT);
            float4 v = make_float4(a0, a1, a2, a3);
            *(float4*)&hs[roff] = v;
        }
        // wave-local LDS visibility: writes above feed reads below within this wave only
        asm volatile("s_waitcnt lgkmcnt(0)" ::: "memory");

        // ---- partial GEMM: this thread's 16 k with register-resident W ----
        float4 acc[8];
#pragma unroll
        for (int b = 0; b < 8; ++b) acc[b] = make_float4(0.f, 0.f, 0.f, 0.f);
        const float4* hs4 = (const float4*)hs;
#pragma unroll
        for (int j = 0; j < 16; ++j) {
            const int k = ks * 16 + j;
            float4 w = Wr[j];
            float4 hA = hs4[k * 2 + 0];           // broadcast h[k][b0..3]
            float4 hB = hs4[k * 2 + 1];           // broadcast h[k][b4..7]
            acc[0].x += w.x * hA.x; acc[0].y += w.y * hA.x; acc[0].z += w.z * hA.x; acc[0].w += w.w * hA.x;
            acc[1].x += w.x * hA.y; acc[1].y += w.y * hA.y; acc[1].z += w.z * hA.y; acc[1].w += w.w * hA.y;
            acc[2].x += w.x * hA.z; acc[2].y += w.y * hA.z; acc[2].z += w.z * hA.z; acc[2].w += w.w * hA.z;
            acc[3].x += w.x * hA.w; acc[3].y += w.y * hA.w; acc[3].z += w.z * hA.w; acc[3].w += w.w * hA.w;
            acc[4].x += w.x * hB.x; acc[4].y += w.y * hB.x; acc[4].z += w.z * hB.x; acc[4].w += w.w * hB.x;
            acc[5].x += w.x * hB.y; acc[5].y += w.y * hB.y; acc[5].z += w.z * hB.y; acc[5].w += w.w * hB.y;
            acc[6].x += w.x * hB.z; acc[6].y += w.y * hB.z; acc[6].z += w.z * hB.z; acc[6].w += w.w * hB.z;
            acc[7].x += w.x * hB.w; acc[7].y += w.y * hB.w; acc[7].z += w.z * hB.w; acc[7].w += w.w * hB.w;
        }

        // pair-combine the two k-slices of each wave, then wave partials via LDS
#pragma unroll
        for (int b = 0; b < 8; ++b) {
            acc[b].x += __shfl_xor(acc[b].x, 32);
            acc[b].y += __shfl_xor(acc[b].y, 32);
            acc[b].z += __shfl_xor(acc[b].z, 32);
            acc[b].w += __shfl_xor(acc[b].w, 32);
        }
        if ((tid & 32) == 0) {
            float* r = &red[(wv * 32 + u) * 33];
#pragma unroll
            for (int b = 0; b < 8; ++b) {
                r[b * 4 + 0] = acc[b].x; r[b * 4 + 1] = acc[b].y;
                r[b * 4 + 2] = acc[b].z; r[b * 4 + 3] = acc[b].w;
            }
        }
        __syncthreads();                         // barrier 1: partials visible

        float h = 0.f;
        if (tid < 256) {
            float si = g4.x, sf = g4.y, sg = g4.z, so = g4.w;
#pragma unroll
            for (int ww = 0; ww < 8; ++ww) {
                const float* r = &red[(ww * 32 + u) * 33 + fb * 4];
                si += r[0]; sf += r[1]; sg += r[2]; so += r[3];
            }
            c = sigf(sf) * c + sigf(si) * tanhf(sg);
            h = sigf(so) * tanhf(c);
            // publish h first — only these stores must drain before the flag
            __hip_atomic_store(&hexg[(t & 1) * 2048 + (ut * 32 + u) * 8 + fb], h,
                               __ATOMIC_RELAXED, __HIP_MEMORY_SCOPE_AGENT);
        }
        __syncthreads();                         // barrier 2: vmcnt(0) drain -> hex visible
        if (tid == 0)
            __hip_atomic_store(&flags[(fbase + ut) * 4], t + 1,
                               __ATOMIC_RELAXED, __HIP_MEMORY_SCOPE_AGENT);
        if (tid < 256) {                         // hout store AFTER flag: off critical path
            int tt = dir ? (t < len_b ? len_b - 1 - t : t) : t;
            hout[(((size_t)(dir * B_ + bt * 8 + fb)) * T_ + tt) * HD_ + ut * 32 + u] = h;
        }
    }
}

// ---------- features: feats[b*T+t][k] = hcat . W_out[k] + b_out[k] ----------
__global__ void feat_k(const float* __restrict__ hout, const float* __restrict__ Wout,
                       const float* __restrict__ bout, float* __restrict__ feats) {
    int tid = threadIdx.x;                 // 192 = 16 pos x 12 tags
    int pl = tid / 12, k = tid % 12;
    int p = blockIdx.x * 16 + pl;          // p = b*256 + t
    const float4* hf = (const float4*)(hout + (size_t)p * HD_);
    const float4* hb = (const float4*)(hout + (size_t)(B_ * T_ + p) * HD_);
    const float4* w0 = (const float4*)(Wout + (size_t)k * 512);
    const float4* w1 = (const float4*)(Wout + (size_t)k * 512 + 256);
    float acc = bout[k];
#pragma unroll 4
    for (int j = 0; j < 64; ++j) {
        float4 h4 = hf[j], v4 = w0[j];
        acc += h4.x * v4.x + h4.y * v4.y + h4.z * v4.z + h4.w * v4.w;
    }
#pragma unroll 4
    for (int j = 0; j < 64; ++j) {
        float4 h4 = hb[j], v4 = w1[j];
        acc += h4.x * v4.x + h4.y * v4.y + h4.z * v4.z + h4.w * v4.w;
    }
    feats[(size_t)p * K_ + k] = acc;
}

// ---------- Viterbi + backtrace: single block, bp nibble-packed in LDS ----------
__global__ __launch_bounds__(512) void viterbi_k(
    const float* __restrict__ feats, const float* __restrict__ trans,
    const int* __restrict__ lens, float* __restrict__ out) {
    __shared__ float fv[2][B_][16];
    __shared__ float tl[K_][16];
    __shared__ unsigned char bp[T_][B_][6];    // 4-bit backpointers, 48KB
    __shared__ int best_last[B_];
    int tid = threadIdx.x;
    int b = tid >> 4, lane = tid & 15;
    if (tid < K_ * K_) tl[tid / 12][tid % 12] = trans[tid];
    if (lane < K_) fv[0][b][lane] = (lane == START_) ? 0.f : NEG_;
    __syncthreads();
    int len = lens[b];
    int pp = 0;
    for (int t = 0; t < T_; ++t) {
        if (lane < K_) {
            float best = fv[pp][b][0] + tl[lane][0];
            int argp = 0;
#pragma unroll
            for (int p = 1; p < K_; ++p) {
                float v = fv[pp][b][p] + tl[lane][p];
                if (v > best) { best = v; argp = p; }   // strict > = first-max (matches jnp.argmax)
            }
            float nb = best + feats[((size_t)b * T_ + t) * K_ + lane];
            fv[pp ^ 1][b][lane] = (t < len) ? nb : fv[pp][b][lane];
            int other = __shfl_xor(argp, 1);
            if ((lane & 1) == 0) bp[t][b][lane >> 1] = (unsigned char)(argp | (other << 4));
        }
        __syncthreads();
        pp ^= 1;
    }
    if (lane == 0) {
        float best = fv[pp][b][0] + tl[STOP_][0];
        int bl = 0;
#pragma unroll
        for (int p = 1; p < K_; ++p) {
            float v = fv[pp][b][p] + tl[STOP_][p];
            if (v > best) { best = v; bl = p; }
        }
        out[b] = best;
        best_last[b] = bl;
    }
    __syncthreads();
    if (lane == 0) {
        int tag = best_last[b];
        for (int t = T_ - 1; t >= 0; --t) {
            int m = (t < len);
            out[B_ + b * T_ + t] = (float)(m ? tag : -1);
            if (m) tag = (bp[t][b][tag >> 1] >> ((tag & 1) * 4)) & 15;
        }
    }
}

extern "C" void kernel_launch(void* const* d_in, const int* in_sizes, int n_in,
                              void* d_out, int out_size, void* d_ws, size_t ws_size,
                              hipStream_t stream) {
    const int*   sent  = (const int*)d_in[0];
    const int*   lens  = (const int*)d_in[1];
    const float* emb   = (const float*)d_in[2];
    const float* Wih_f = (const float*)d_in[3];
    const float* Whh_f = (const float*)d_in[4];
    const float* bih_f = (const float*)d_in[5];
    const float* bhh_f = (const float*)d_in[6];
    const float* Wih_b = (const float*)d_in[7];
    const float* Whh_b = (const float*)d_in[8];
    const float* bih_b = (const float*)d_in[9];
    const float* bhh_b = (const float*)d_in[10];
    const float* h0    = (const float*)d_in[11];
    const float* c0    = (const float*)d_in[12];
    const float* Wout  = (const float*)d_in[13];
    const float* bout  = (const float*)d_in[14];
    const float* trans = (const float*)d_in[15];
    float* out = (float*)d_out;

    char* ws = (char*)d_ws;
    int*   tokA  = (int*)ws;                                            // 64 KB
    float* WhhT  = (float*)(ws + 65536);                                // 2 MB
    float* G     = (float*)(ws + 65536 + 2097152);                      // 67.1 MB
    float* hout  = (float*)(ws + 65536 + 2097152 + 67108864);           // 16.8 MB
    float* feats = (float*)(ws + 65536 + 2097152 + 67108864 + 16777216);// 0.39 MB
    float* hex   = (float*)(ws + 86441984);                             // 128 KB h-exchange
    int*   flags = (int*)(ws + 86441984 + 131072);                      // 1 KB (64 flags x16B)

    tok_gather<<<64, 256, 0, stream>>>(sent, lens, tokA);
    whh_tr<<<512, 256, 0, stream>>>(Whh_f, Whh_b, WhhT);
    init_flags<<<1, 256, 0, stream>>>(flags);
    in_gemm<<<dim3(8, 64, 2), 256, 0, stream>>>(emb, tokA, Wih_f, Wih_b,
                                                bih_f, bhh_f, bih_b, bhh_b, G);
    lstm_rec4<<<64, 512, 0, stream>>>(WhhT, G, h0, c0, lens, hout, hex, flags);
    feat_k<<<512, 192, 0, stream>>>(hout, Wout, bout, feats);
    viterbi_k<<<1, 512, 0, stream>>>(feats, trans, lens, out);
}

// Round 5
// 1297.373 us; speedup vs baseline: 2.2515x; 1.0386x over previous
//
#include <hip/hip_runtime.h>
#include <math.h>

#define T_ 256
#define B_ 32
#define E_ 256
#define HD_ 256
#define NG_ 1024
#define K_ 12
#define START_ 10
#define STOP_ 11
#define NEG_ -10000.0f
#define MAGICU 0x40000000u   // 2.0f — |h|<1 so h can never be this bit pattern

__device__ __forceinline__ float sigf(float x) { return 1.0f / (1.0f + expf(-x)); }

// ---------- token gather (bwd dir reversed within each sequence length) ----------
__global__ void tok_gather(const int* __restrict__ sent, const int* __restrict__ lens,
                           int* __restrict__ tokA) {
    int e = blockIdx.x * 256 + threadIdx.x;      // 0..16383 = [dir][t*32+b]
    int dir = e >> 13, m = e & 8191, t = m >> 5, b = m & 31;
    int len = lens[b];
    int tt = dir ? (t < len ? len - 1 - t : t) : t;
    tokA[e] = sent[b * T_ + tt];
}

// ---------- Whh^T into [dir][k][u*4+gate] (unit-major gate packing) ----------
__global__ void whh_tr(const float* __restrict__ Wf, const float* __restrict__ Wb,
                       float* __restrict__ WT) {
    int dir = blockIdx.x >> 8, k = blockIdx.x & 255, u = threadIdx.x;
    const float* W = dir ? Wb : Wf;
    float4 v;
    v.x = W[(0 * HD_ + u) * HD_ + k];   // i
    v.y = W[(1 * HD_ + u) * HD_ + k];   // f
    v.z = W[(2 * HD_ + u) * HD_ + k];   // g
    v.w = W[(3 * HD_ + u) * HD_ + k];   // o
    ((float4*)(WT + ((size_t)dir * 256 + k) * NG_))[u] = v;
}

// ---------- fill the h-exchange ring with the MAGIC sentinel ----------
__global__ void hex_init(float* __restrict__ hex) {
    int i = blockIdx.x * 256 + threadIdx.x;      // 4096 blocks -> 16 MB
    float4 m = make_float4(2.0f, 2.0f, 2.0f, 2.0f);
    ((float4*)hex)[i] = m;
}

// ---------- fused embedding-gather + input GEMM: G[dir][t*32+b][u*4+g] = x@Wih^T + bih + bhh ----------
__global__ __launch_bounds__(256) void in_gemm(
    const float* __restrict__ emb, const int* __restrict__ tokA,
    const float* __restrict__ Wih_f, const float* __restrict__ Wih_b,
    const float* __restrict__ bih_f, const float* __restrict__ bhh_f,
    const float* __restrict__ bih_b, const float* __restrict__ bhh_b,
    float* __restrict__ G) {
    const int dir = blockIdx.z;
    const int n0 = blockIdx.x * 128, m0 = blockIdx.y * 128;
    const float* Wih = dir ? Wih_b : Wih_f;
    const float* bihp = dir ? bih_b : bih_f;
    const float* bhhp = dir ? bhh_b : bhh_f;
    __shared__ float As[8][128];
    __shared__ float Bs[8][128];
    const int tid = threadIdx.x;
    const int rs = tid >> 1, kc = (tid & 1) * 4;
    const int tok = tokA[dir * 8192 + m0 + rs];
    const float* arow = emb + (size_t)tok * E_;
    const int np = n0 + rs;
    const int wrow = ((np & 3) << 8) | (np >> 2);     // permuted col n'=u*4+g -> Wih row g*256+u
    const float* brow = Wih + (size_t)wrow * E_;
    const int ty = tid >> 4, tx = tid & 15;

    float acc[8][8];
#pragma unroll
    for (int i = 0; i < 8; ++i)
#pragma unroll
        for (int j = 0; j < 8; ++j) acc[i][j] = 0.f;

    for (int k0 = 0; k0 < E_; k0 += 8) {
        float4 av = *(const float4*)(arow + k0 + kc);
        float4 bv = *(const float4*)(brow + k0 + kc);
        __syncthreads();
        As[kc + 0][rs] = av.x; As[kc + 1][rs] = av.y; As[kc + 2][rs] = av.z; As[kc + 3][rs] = av.w;
        Bs[kc + 0][rs] = bv.x; Bs[kc + 1][rs] = bv.y; Bs[kc + 2][rs] = bv.z; Bs[kc + 3][rs] = bv.w;
        __syncthreads();
#pragma unroll
        for (int k = 0; k < 8; ++k) {
            float4 a0 = *(const float4*)&As[k][ty * 8];
            float4 a1 = *(const float4*)&As[k][ty * 8 + 4];
            float4 b0 = *(const float4*)&Bs[k][tx * 8];
            float4 b1 = *(const float4*)&Bs[k][tx * 8 + 4];
            float af8[8] = {a0.x, a0.y, a0.z, a0.w, a1.x, a1.y, a1.z, a1.w};
            float bf8[8] = {b0.x, b0.y, b0.z, b0.w, b1.x, b1.y, b1.z, b1.w};
#pragma unroll
            for (int i = 0; i < 8; ++i)
#pragma unroll
                for (int j = 0; j < 8; ++j) acc[i][j] += af8[i] * bf8[j];
        }
    }
    float bias[8];
#pragma unroll
    for (int j = 0; j < 8; ++j) {
        int nn = n0 + tx * 8 + j;
        int wr = ((nn & 3) << 8) | (nn >> 2);
        bias[j] = bihp[wr] + bhhp[wr];
    }
#pragma unroll
    for (int i = 0; i < 8; ++i) {
        int m = m0 + ty * 8 + i;
        float* gp = G + ((size_t)dir * 8192 + m) * NG_ + n0 + tx * 8;
        float4 o0 = {acc[i][0] + bias[0], acc[i][1] + bias[1], acc[i][2] + bias[2], acc[i][3] + bias[3]};
        float4 o1 = {acc[i][4] + bias[4], acc[i][5] + bias[5], acc[i][6] + bias[6], acc[i][7] + bias[7]};
        *(float4*)gp = o0;
        *(float4*)(gp + 4) = o1;
    }
}

// ---------- recurrence v5: v4 grid (64 WGs = dir x 4 bt x 8 ut, 512 thr), W in regs,
// T-deep self-validating h exchange (poll data vs MAGIC) — no flags, no store drain.
__global__ __launch_bounds__(512, 2) void lstm_rec5(
    const float* __restrict__ WhhT, const float* __restrict__ G,
    const float* __restrict__ h0, const float* __restrict__ c0,
    const int* __restrict__ lens, float* __restrict__ hout,
    float* __restrict__ hex) {
    const int wg = blockIdx.x;                   // dir*32 + bt*8 + ut
    const int dir = wg >> 5, bt = (wg >> 3) & 3, ut = wg & 7;
    const int tid = threadIdx.x;
    const int u = tid & 31;                      // unit within tile
    const int ks = tid >> 5;                     // k-slice 0..15 (16 k each)
    const int fb = tid >> 5;                     // (tid<256) batch within group
    const int wv = tid >> 6;                     // wave 0..7  <-> producer WG wv
    const int lane = tid & 63;

    __shared__ float hs[2048];                   // h(t-1): [k][b], b fast (wave-private ranges)
    __shared__ float red[256 * 33];              // wave partials, pitch 33

    const int Tmax = lens[bt * 8];               // lens sorted desc -> group max

    float c = 0.f; int len_b = 0;
    if (tid < 256) {
        c = c0[(dir * B_ + bt * 8 + fb) * HD_ + ut * 32 + u];
        len_b = lens[bt * 8 + fb];
    }

    // ---- W slice into registers: 16 float4/thread, loaded once ----
    const float4* WT4 = (const float4*)(WhhT + (size_t)dir * 256 * NG_);
    float4 Wr[16];
#pragma unroll
    for (int j = 0; j < 16; ++j) Wr[j] = WT4[(((ks * 16 + j)) << 8) + ut * 32 + u];

    const float* Gd = G + (size_t)dir * 8192 * NG_;
    float* hexg = hex + (size_t)(dir * 4 + bt) * T_ * 2048;  // [t][k*8+b]
    const int roff = wv * 256 + lane * 4;        // this wave's slice = producer WG wv's slice

    for (int t = 0; t < Tmax; ++t) {
        // G pre-activation for this step — issue before the poll so L3 latency hides
        float4 g4 = make_float4(0.f, 0.f, 0.f, 0.f);
        if (tid < 256)
            g4 = ((const float4*)(Gd + ((size_t)t * B_ + bt * 8 + fb) * NG_))[ut * 32 + u];

        if (t == 0) {
            // stage h0 (transposed gather, once)
            const int base = (dir * B_ + bt * 8) * HD_;
            const int rk = wv * 32 + (lane >> 1), b4 = (lane & 1) * 4;
            float4 v;
            v.x = h0[base + (b4 + 0) * HD_ + rk];
            v.y = h0[base + (b4 + 1) * HD_ + rk];
            v.z = h0[base + (b4 + 2) * HD_ + rk];
            v.w = h0[base + (b4 + 3) * HD_ + rk];
            *(float4*)&hs[roff] = v;
        } else {
            // poll the data itself: a word is valid the moment it differs from MAGIC
            const float* src = hexg + (size_t)(t - 1) * 2048 + roff;
            float a0, a1, a2, a3; int it = 0;
            for (;;) {
                a0 = __hip_atomic_load(src + 0, __ATOMIC_RELAXED, __HIP_MEMORY_SCOPE_AGENT);
                a1 = __hip_atomic_load(src + 1, __ATOMIC_RELAXED, __HIP_MEMORY_SCOPE_AGENT);
                a2 = __hip_atomic_load(src + 2, __ATOMIC_RELAXED, __HIP_MEMORY_SCOPE_AGENT);
                a3 = __hip_atomic_load(src + 3, __ATOMIC_RELAXED, __HIP_MEMORY_SCOPE_AGENT);
                if (!(__float_as_uint(a0) == MAGICU || __float_as_uint(a1) == MAGICU ||
                      __float_as_uint(a2) == MAGICU || __float_as_uint(a3) == MAGICU)) break;
                __builtin_amdgcn_s_sleep(1);
                if (++it > (1 << 22)) break;     // bail -> visible failure, not hang
            }
            float4 v = make_float4(a0, a1, a2, a3);
            *(float4*)&hs[roff] = v;
        }
        // wave-local LDS visibility: writes above feed reads below within this wave only
        asm volatile("s_waitcnt lgkmcnt(0)" ::: "memory");

        // ---- partial GEMM: this thread's 16 k with register-resident W ----
        float4 acc[8];
#pragma unroll
        for (int b = 0; b < 8; ++b) acc[b] = make_float4(0.f, 0.f, 0.f, 0.f);
        const float4* hs4 = (const float4*)hs;
#pragma unroll
        for (int j = 0; j < 16; ++j) {
            const int k = ks * 16 + j;
            float4 w = Wr[j];
            float4 hA = hs4[k * 2 + 0];           // broadcast h[k][b0..3]
            float4 hB = hs4[k * 2 + 1];           // broadcast h[k][b4..7]
            acc[0].x += w.x * hA.x; acc[0].y += w.y * hA.x; acc[0].z += w.z * hA.x; acc[0].w += w.w * hA.x;
            acc[1].x += w.x * hA.y; acc[1].y += w.y * hA.y; acc[1].z += w.z * hA.y; acc[1].w += w.w * hA.y;
            acc[2].x += w.x * hA.z; acc[2].y += w.y * hA.z; acc[2].z += w.z * hA.z; acc[2].w += w.w * hA.z;
            acc[3].x += w.x * hA.w; acc[3].y += w.y * hA.w; acc[3].z += w.z * hA.w; acc[3].w += w.w * hA.w;
            acc[4].x += w.x * hB.x; acc[4].y += w.y * hB.x; acc[4].z += w.z * hB.x; acc[4].w += w.w * hB.x;
            acc[5].x += w.x * hB.y; acc[5].y += w.y * hB.y; acc[5].z += w.z * hB.y; acc[5].w += w.w * hB.y;
            acc[6].x += w.x * hB.z; acc[6].y += w.y * hB.z; acc[6].z += w.z * hB.z; acc[6].w += w.w * hB.z;
            acc[7].x += w.x * hB.w; acc[7].y += w.y * hB.w; acc[7].z += w.z * hB.w; acc[7].w += w.w * hB.w;
        }

        // pair-combine the two k-slices of each wave, then wave partials via LDS
#pragma unroll
        for (int b = 0; b < 8; ++b) {
            acc[b].x += __shfl_xor(acc[b].x, 32);
            acc[b].y += __shfl_xor(acc[b].y, 32);
            acc[b].z += __shfl_xor(acc[b].z, 32);
            acc[b].w += __shfl_xor(acc[b].w, 32);
        }
        if ((tid & 32) == 0) {
            float* r = &red[(wv * 32 + u) * 33];
#pragma unroll
            for (int b = 0; b < 8; ++b) {
                r[b * 4 + 0] = acc[b].x; r[b * 4 + 1] = acc[b].y;
                r[b * 4 + 2] = acc[b].z; r[b * 4 + 3] = acc[b].w;
            }
        }
        __syncthreads();                         // partials visible to waves 0-3

        float h = 0.f;
        if (tid < 256) {
            float si = g4.x, sf = g4.y, sg = g4.z, so = g4.w;
#pragma unroll
            for (int ww = 0; ww < 8; ++ww) {
                const float* r = &red[(ww * 32 + u) * 33 + fb * 4];
                si += r[0]; sf += r[1]; sg += r[2]; so += r[3];
            }
            c = sigf(sf) * c + sigf(si) * tanhf(sg);
            h = sigf(so) * tanhf(c);
            // publish: store is self-validating, no drain/flag needed
            __hip_atomic_store(&hexg[(size_t)t * 2048 + (ut * 32 + u) * 8 + fb], h,
                               __ATOMIC_RELAXED, __HIP_MEMORY_SCOPE_AGENT);
            int tt = dir ? (t < len_b ? len_b - 1 - t : t) : t;
            hout[(((size_t)(dir * B_ + bt * 8 + fb)) * T_ + tt) * HD_ + ut * 32 + u] = h;
        }
        // rendezvous only (no vmcnt drain): protects single-buffer red[] reuse at t+1.
        // Waves' red reads are data-dependency-complete before arriving here.
        asm volatile("s_waitcnt lgkmcnt(0)\n\ts_barrier" ::: "memory");
    }
}

// ---------- features: feats[b*T+t][k] = hcat . W_out[k] + b_out[k] ----------
__global__ void feat_k(const float* __restrict__ hout, const float* __restrict__ Wout,
                       const float* __restrict__ bout, float* __restrict__ feats) {
    int tid = threadIdx.x;                 // 192 = 16 pos x 12 tags
    int pl = tid / 12, k = tid % 12;
    int p = blockIdx.x * 16 + pl;          // p = b*256 + t
    const float4* hf = (const float4*)(hout + (size_t)p * HD_);
    const float4* hb = (const float4*)(hout + (size_t)(B_ * T_ + p) * HD_);
    const float4* w0 = (const float4*)(Wout + (size_t)k * 512);
    const float4* w1 = (const float4*)(Wout + (size_t)k * 512 + 256);
    float acc = bout[k];
#pragma unroll 4
    for (int j = 0; j < 64; ++j) {
        float4 h4 = hf[j], v4 = w0[j];
        acc += h4.x * v4.x + h4.y * v4.y + h4.z * v4.z + h4.w * v4.w;
    }
#pragma unroll 4
    for (int j = 0; j < 64; ++j) {
        float4 h4 = hb[j], v4 = w1[j];
        acc += h4.x * v4.x + h4.y * v4.y + h4.z * v4.z + h4.w * v4.w;
    }
    feats[(size_t)p * K_ + k] = acc;
}

// ---------- Viterbi + backtrace: single block, feats prefetch, bp nibble-packed ----------
__global__ __launch_bounds__(512) void viterbi_k(
    const float* __restrict__ feats, const float* __restrict__ trans,
    const int* __restrict__ lens, float* __restrict__ out) {
    __shared__ float fv[2][B_][16];
    __shared__ float tl[K_][16];
    __shared__ unsigned char bp[T_][B_][6];    // 4-bit backpointers, 48KB
    __shared__ int best_last[B_];
    int tid = threadIdx.x;
    int b = tid >> 4, lane = tid & 15;
    if (tid < K_ * K_) tl[tid / 12][tid % 12] = trans[tid];
    if (lane < K_) fv[0][b][lane] = (lane == START_) ? 0.f : NEG_;
    __syncthreads();
    int len = lens[b];
    int pp = 0;
    float f_cur = 0.f;
    if (lane < K_) f_cur = feats[(size_t)b * T_ * K_ + lane];
    for (int t = 0; t < T_; ++t) {
        float f_nxt = 0.f;                       // prefetch t+1 before the compute chain
        if (t + 1 < T_ && lane < K_) f_nxt = feats[((size_t)b * T_ + t + 1) * K_ + lane];
        if (lane < K_) {
            float best = fv[pp][b][0] + tl[lane][0];
            int argp = 0;
#pragma unroll
            for (int p = 1; p < K_; ++p) {
                float v = fv[pp][b][p] + tl[lane][p];
                if (v > best) { best = v; argp = p; }   // strict > = first-max (matches jnp.argmax)
            }
            float nb = best + f_cur;
            fv[pp ^ 1][b][lane] = (t < len) ? nb : fv[pp][b][lane];
            int other = __shfl_xor(argp, 1);
            if ((lane & 1) == 0) bp[t][b][lane >> 1] = (unsigned char)(argp | (other << 4));
        }
        __syncthreads();
        pp ^= 1;
        f_cur = f_nxt;
    }
    if (lane == 0) {
        float best = fv[pp][b][0] + tl[STOP_][0];
        int bl = 0;
#pragma unroll
        for (int p = 1; p < K_; ++p) {
            float v = fv[pp][b][p] + tl[STOP_][p];
            if (v > best) { best = v; bl = p; }
        }
        out[b] = best;
        best_last[b] = bl;
    }
    __syncthreads();
    if (lane == 0) {
        int tag = best_last[b];
        for (int t = T_ - 1; t >= 0; --t) {
            int m = (t < len);
            out[B_ + b * T_ + t] = (float)(m ? tag : -1);
            if (m) tag = (bp[t][b][tag >> 1] >> ((tag & 1) * 4)) & 15;
        }
    }
}

extern "C" void kernel_launch(void* const* d_in, const int* in_sizes, int n_in,
                              void* d_out, int out_size, void* d_ws, size_t ws_size,
                              hipStream_t stream) {
    const int*   sent  = (const int*)d_in[0];
    const int*   lens  = (const int*)d_in[1];
    const float* emb   = (const float*)d_in[2];
    const float* Wih_f = (const float*)d_in[3];
    const float* Whh_f = (const float*)d_in[4];
    const float* bih_f = (const float*)d_in[5];
    const float* bhh_f = (const float*)d_in[6];
    const float* Wih_b = (const float*)d_in[7];
    const float* Whh_b = (const float*)d_in[8];
    const float* bih_b = (const float*)d_in[9];
    const float* bhh_b = (const float*)d_in[10];
    const float* h0    = (const float*)d_in[11];
    const float* c0    = (const float*)d_in[12];
    const float* Wout  = (const float*)d_in[13];
    const float* bout  = (const float*)d_in[14];
    const float* trans = (const float*)d_in[15];
    float* out = (float*)d_out;

    char* ws = (char*)d_ws;
    int*   tokA  = (int*)ws;                                            // 64 KB
    float* WhhT  = (float*)(ws + 65536);                                // 2 MB
    float* G     = (float*)(ws + 65536 + 2097152);                      // 67.1 MB
    float* hout  = (float*)(ws + 65536 + 2097152 + 67108864);           // 16.8 MB
    float* feats = (float*)(ws + 65536 + 2097152 + 67108864 + 16777216);// 0.39 MB
    float* hex   = (float*)(ws + 86441984);                             // 16 MB T-deep h-exchange

    tok_gather<<<64, 256, 0, stream>>>(sent, lens, tokA);
    whh_tr<<<512, 256, 0, stream>>>(Whh_f, Whh_b, WhhT);
    hex_init<<<4096, 256, 0, stream>>>(hex);
    in_gemm<<<dim3(8, 64, 2), 256, 0, stream>>>(emb, tokA, Wih_f, Wih_b,
                                                bih_f, bhh_f, bih_b, bhh_b, G);
    lstm_rec5<<<64, 512, 0, stream>>>(WhhT, G, h0, c0, lens, hout, hex);
    feat_k<<<512, 192, 0, stream>>>(hout, Wout, bout, feats);
    viterbi_k<<<1, 512, 0, stream>>>(feats, trans, lens, out);
}

// Round 6
// 1246.040 us; speedup vs baseline: 2.3443x; 1.0412x over previous
//
#include <hip/hip_runtime.h>
#include <math.h>

#define T_ 256
#define B_ 32
#define E_ 256
#define HD_ 256
#define NG_ 1024
#define K_ 12
#define START_ 10
#define STOP_ 11
#define NEG_ -10000.0f
#define MAGICU 0x40000000u   // 2.0f — |h|<1 so h can never be this bit pattern

typedef float f4_t __attribute__((ext_vector_type(4)));

__device__ __forceinline__ float sigf(float x) { return 1.0f / (1.0f + expf(-x)); }

// ---------- token gather (bwd dir reversed within each sequence length) ----------
__global__ void tok_gather(const int* __restrict__ sent, const int* __restrict__ lens,
                           int* __restrict__ tokA) {
    int e = blockIdx.x * 256 + threadIdx.x;      // 0..16383 = [dir][t*32+b]
    int dir = e >> 13, m = e & 8191, t = m >> 5, b = m & 31;
    int len = lens[b];
    int tt = dir ? (t < len ? len - 1 - t : t) : t;
    tokA[e] = sent[b * T_ + tt];
}

// ---------- Whh^T into [dir][k][u*4+gate] (unit-major gate packing) ----------
__global__ void whh_tr(const float* __restrict__ Wf, const float* __restrict__ Wb,
                       float* __restrict__ WT) {
    int dir = blockIdx.x >> 8, k = blockIdx.x & 255, u = threadIdx.x;
    const float* W = dir ? Wb : Wf;
    float4 v;
    v.x = W[(0 * HD_ + u) * HD_ + k];   // i
    v.y = W[(1 * HD_ + u) * HD_ + k];   // f
    v.z = W[(2 * HD_ + u) * HD_ + k];   // g
    v.w = W[(3 * HD_ + u) * HD_ + k];   // o
    ((float4*)(WT + ((size_t)dir * 256 + k) * NG_))[u] = v;
}

// ---------- fill the h-exchange ring with the MAGIC sentinel ----------
// (separate dispatch: kernel-end release makes these stores visible to the
//  L2-bypassing sc1 polls in lstm_rec6)
__global__ void hex_init(float* __restrict__ hex) {
    int i = blockIdx.x * 256 + threadIdx.x;      // 4096 blocks -> 16 MB
    float4 m = make_float4(2.0f, 2.0f, 2.0f, 2.0f);
    ((float4*)hex)[i] = m;
}

// ---------- fused embedding-gather + input GEMM: G[dir][t*32+b][u*4+g] = x@Wih^T + bih + bhh ----------
__global__ __launch_bounds__(256) void in_gemm(
    const float* __restrict__ emb, const int* __restrict__ tokA,
    const float* __restrict__ Wih_f, const float* __restrict__ Wih_b,
    const float* __restrict__ bih_f, const float* __restrict__ bhh_f,
    const float* __restrict__ bih_b, const float* __restrict__ bhh_b,
    float* __restrict__ G) {
    const int dir = blockIdx.z;
    const int n0 = blockIdx.x * 128, m0 = blockIdx.y * 128;
    const float* Wih = dir ? Wih_b : Wih_f;
    const float* bihp = dir ? bih_b : bih_f;
    const float* bhhp = dir ? bhh_b : bhh_f;
    __shared__ float As[8][128];
    __shared__ float Bs[8][128];
    const int tid = threadIdx.x;
    const int rs = tid >> 1, kc = (tid & 1) * 4;
    const int tok = tokA[dir * 8192 + m0 + rs];
    const float* arow = emb + (size_t)tok * E_;
    const int np = n0 + rs;
    const int wrow = ((np & 3) << 8) | (np >> 2);     // permuted col n'=u*4+g -> Wih row g*256+u
    const float* brow = Wih + (size_t)wrow * E_;
    const int ty = tid >> 4, tx = tid & 15;

    float acc[8][8];
#pragma unroll
    for (int i = 0; i < 8; ++i)
#pragma unroll
        for (int j = 0; j < 8; ++j) acc[i][j] = 0.f;

    for (int k0 = 0; k0 < E_; k0 += 8) {
        float4 av = *(const float4*)(arow + k0 + kc);
        float4 bv = *(const float4*)(brow + k0 + kc);
        __syncthreads();
        As[kc + 0][rs] = av.x; As[kc + 1][rs] = av.y; As[kc + 2][rs] = av.z; As[kc + 3][rs] = av.w;
        Bs[kc + 0][rs] = bv.x; Bs[kc + 1][rs] = bv.y; Bs[kc + 2][rs] = bv.z; Bs[kc + 3][rs] = bv.w;
        __syncthreads();
#pragma unroll
        for (int k = 0; k < 8; ++k) {
            float4 a0 = *(const float4*)&As[k][ty * 8];
            float4 a1 = *(const float4*)&As[k][ty * 8 + 4];
            float4 b0 = *(const float4*)&Bs[k][tx * 8];
            float4 b1 = *(const float4*)&Bs[k][tx * 8 + 4];
            float af8[8] = {a0.x, a0.y, a0.z, a0.w, a1.x, a1.y, a1.z, a1.w};
            float bf8[8] = {b0.x, b0.y, b0.z, b0.w, b1.x, b1.y, b1.z, b1.w};
#pragma unroll
            for (int i = 0; i < 8; ++i)
#pragma unroll
                for (int j = 0; j < 8; ++j) acc[i][j] += af8[i] * bf8[j];
        }
    }
    float bias[8];
#pragma unroll
    for (int j = 0; j < 8; ++j) {
        int nn = n0 + tx * 8 + j;
        int wr = ((nn & 3) << 8) | (nn >> 2);
        bias[j] = bihp[wr] + bhhp[wr];
    }
#pragma unroll
    for (int i = 0; i < 8; ++i) {
        int m = m0 + ty * 8 + i;
        float* gp = G + ((size_t)dir * 8192 + m) * NG_ + n0 + tx * 8;
        float4 o0 = {acc[i][0] + bias[0], acc[i][1] + bias[1], acc[i][2] + bias[2], acc[i][3] + bias[3]};
        float4 o1 = {acc[i][4] + bias[4], acc[i][5] + bias[5], acc[i][6] + bias[6], acc[i][7] + bias[7]};
        *(float4*)gp = o0;
        *(float4*)(gp + 4) = o1;
    }
}

// ---------- recurrence v6: 64 WGs (dir x 4 bt x 8 ut), W in regs. Publish = one
// coalesced 1KB dwordx4 burst by wave 0 only (hex layout [t][b][u], self-validating
// vs MAGIC); no hout (hex IS the h history); own-slice read from LDS. ----------
__global__ __launch_bounds__(512, 2) void lstm_rec6(
    const float* __restrict__ WhhT, const float* __restrict__ G,
    const float* __restrict__ h0, const float* __restrict__ c0,
    const int* __restrict__ lens, float* __restrict__ hex) {
    const int wg = blockIdx.x;                   // dir*32 + bt*8 + ut
    const int dir = wg >> 5, bt = (wg >> 3) & 3, ut = wg & 7;
    const int tid = threadIdx.x;
    const int u = tid & 31;                      // unit within tile
    const int ks = tid >> 5;                     // k-slice 0..15 (16 k each)
    const int fb = tid >> 5;                     // (tid<256) batch within group
    const int wv = tid >> 6;                     // wave 0..7  <-> producer WG wv
    const int lane = tid & 63;

    __shared__ float hs[2048];                   // h(t-1): [k][b], b fast (wave-private slices)
    __shared__ float red[256 * 33];              // wave partials, pitch 33
    __shared__ float hT[256];                    // this WG's h slice: [fb*32+u]

    const int Tmax = lens[bt * 8];               // lens sorted desc -> group max

    float c = 0.f;
    if (tid < 256)
        c = c0[(dir * B_ + bt * 8 + fb) * HD_ + ut * 32 + u];

    // ---- W slice into registers: 16 float4/thread, loaded once ----
    const float4* WT4 = (const float4*)(WhhT + (size_t)dir * 256 * NG_);
    float4 Wr[16];
#pragma unroll
    for (int j = 0; j < 16; ++j) Wr[j] = WT4[(((ks * 16 + j)) << 8) + ut * 32 + u];

    const float* Gd = G + (size_t)dir * 8192 * NG_;
    float* hexg = hex + (size_t)(dir * 4 + bt) * T_ * 2048;  // [t][b*256+u]
    // consumer mapping: lane l -> batch bl = l>>3, k-chunk jl = l&7 (4 k's)
    const int bl = lane >> 3, jl = lane & 7;

    for (int t = 0; t < Tmax; ++t) {
        // G pre-activation for this step — issue before the poll so latency hides
        float4 g4 = make_float4(0.f, 0.f, 0.f, 0.f);
        if (tid < 256)
            g4 = ((const float4*)(Gd + ((size_t)t * B_ + bt * 8 + fb) * NG_))[ut * 32 + u];

        if (t == 0) {
            // stage h0 into own wave's hs slice ([k][b], once)
            const int base = (dir * B_ + bt * 8) * HD_;
            const int rk = wv * 32 + (lane >> 1), b4 = (lane & 1) * 4;
            float4 v;
            v.x = h0[base + (b4 + 0) * HD_ + rk];
            v.y = h0[base + (b4 + 1) * HD_ + rk];
            v.z = h0[base + (b4 + 2) * HD_ + rk];
            v.w = h0[base + (b4 + 3) * HD_ + rk];
            *(float4*)&hs[wv * 256 + lane * 4] = v;
        } else {
            float4 hv;
            if (wv == ut) {
                // own slice: straight from LDS (written before last barrier)
                hv = *(const float4*)&hT[lane * 4];
            } else {
                // poll peer WG wv's coalesced publish; each dword self-validates
                const float* src = hexg + (size_t)(t - 1) * 2048 + bl * 256 + wv * 32 + jl * 4;
                float a0, a1, a2, a3; int it = 0;
                for (;;) {
                    a0 = __hip_atomic_load(src + 0, __ATOMIC_RELAXED, __HIP_MEMORY_SCOPE_AGENT);
                    a1 = __hip_atomic_load(src + 1, __ATOMIC_RELAXED, __HIP_MEMORY_SCOPE_AGENT);
                    a2 = __hip_atomic_load(src + 2, __ATOMIC_RELAXED, __HIP_MEMORY_SCOPE_AGENT);
                    a3 = __hip_atomic_load(src + 3, __ATOMIC_RELAXED, __HIP_MEMORY_SCOPE_AGENT);
                    if (!(__float_as_uint(a0) == MAGICU || __float_as_uint(a1) == MAGICU ||
                          __float_as_uint(a2) == MAGICU || __float_as_uint(a3) == MAGICU)) break;
                    __builtin_amdgcn_s_sleep(1);
                    if (++it > (1 << 22)) break;     // bail -> visible failure, not hang
                }
                hv = make_float4(a0, a1, a2, a3);
            }
            // transpose into wave-private hs slice: hs[(k)*8 + b]
            const int kb = wv * 32 + jl * 4;
            hs[(kb + 0) * 8 + bl] = hv.x;
            hs[(kb + 1) * 8 + bl] = hv.y;
            hs[(kb + 2) * 8 + bl] = hv.z;
            hs[(kb + 3) * 8 + bl] = hv.w;
        }
        // wave-local LDS visibility (slices are wave-private)
        asm volatile("s_waitcnt lgkmcnt(0)" ::: "memory");

        // ---- partial GEMM: this thread's 16 k with register-resident W ----
        float4 acc[8];
#pragma unroll
        for (int b = 0; b < 8; ++b) acc[b] = make_float4(0.f, 0.f, 0.f, 0.f);
        const float4* hs4 = (const float4*)hs;
#pragma unroll
        for (int j = 0; j < 16; ++j) {
            const int k = ks * 16 + j;
            float4 w = Wr[j];
            float4 hA = hs4[k * 2 + 0];           // broadcast h[k][b0..3]
            float4 hB = hs4[k * 2 + 1];           // broadcast h[k][b4..7]
            acc[0].x += w.x * hA.x; acc[0].y += w.y * hA.x; acc[0].z += w.z * hA.x; acc[0].w += w.w * hA.x;
            acc[1].x += w.x * hA.y; acc[1].y += w.y * hA.y; acc[1].z += w.z * hA.y; acc[1].w += w.w * hA.y;
            acc[2].x += w.x * hA.z; acc[2].y += w.y * hA.z; acc[2].z += w.z * hA.z; acc[2].w += w.w * hA.z;
            acc[3].x += w.x * hA.w; acc[3].y += w.y * hA.w; acc[3].z += w.z * hA.w; acc[3].w += w.w * hA.w;
            acc[4].x += w.x * hB.x; acc[4].y += w.y * hB.x; acc[4].z += w.z * hB.x; acc[4].w += w.w * hB.x;
            acc[5].x += w.x * hB.y; acc[5].y += w.y * hB.y; acc[5].z += w.z * hB.y; acc[5].w += w.w * hB.y;
            acc[6].x += w.x * hB.z; acc[6].y += w.y * hB.z; acc[6].z += w.z * hB.z; acc[6].w += w.w * hB.z;
            acc[7].x += w.x * hB.w; acc[7].y += w.y * hB.w; acc[7].z += w.z * hB.w; acc[7].w += w.w * hB.w;
        }

        // pair-combine the two k-slices of each wave, then wave partials via LDS
#pragma unroll
        for (int b = 0; b < 8; ++b) {
            acc[b].x += __shfl_xor(acc[b].x, 32);
            acc[b].y += __shfl_xor(acc[b].y, 32);
            acc[b].z += __shfl_xor(acc[b].z, 32);
            acc[b].w += __shfl_xor(acc[b].w, 32);
        }
        if ((tid & 32) == 0) {
            float* r = &red[(wv * 32 + u) * 33];
#pragma unroll
            for (int b = 0; b < 8; ++b) {
                r[b * 4 + 0] = acc[b].x; r[b * 4 + 1] = acc[b].y;
                r[b * 4 + 2] = acc[b].z; r[b * 4 + 3] = acc[b].w;
            }
        }
        __syncthreads();                         // barrier 1: partials visible

        if (tid < 256) {
            float si = g4.x, sf = g4.y, sg = g4.z, so = g4.w;
#pragma unroll
            for (int ww = 0; ww < 8; ++ww) {
                const float* r = &red[(ww * 32 + u) * 33 + fb * 4];
                si += r[0]; sf += r[1]; sg += r[2]; so += r[3];
            }
            c = sigf(sf) * c + sigf(si) * tanhf(sg);
            float h = sigf(so) * tanhf(c);
            hT[fb * 32 + u] = h;                 // stride-1, conflict-free
        }
        // barrier 2: hT complete (each wave drains its LDS ops first), red[] reusable
        asm volatile("s_waitcnt lgkmcnt(0)\n\ts_barrier" ::: "memory");

        if (wv == 0) {
            // single coalesced 1KB publish: 64 lanes x dwordx4, agent-coherent
            f4_t hv = *(const f4_t*)&hT[lane * 4];
            float* dst = hexg + (size_t)t * 2048 + (lane >> 3) * 256 + ut * 32 + (lane & 7) * 4;
            asm volatile("global_store_dwordx4 %0, %1, off sc0 sc1"
                         :: "v"(dst), "v"(hv) : "memory");
        }
    }
}

// ---------- features from hex: feats[b*T+t][k] = hcat . W_out[k] + b_out[k] ----------
__global__ void feat_k(const float* __restrict__ hex, const int* __restrict__ lens,
                       const float* __restrict__ Wout, const float* __restrict__ bout,
                       float* __restrict__ feats) {
    int tid = threadIdx.x;                 // 192 = 16 pos x 12 tags
    int pl = tid / 12, k = tid % 12;
    int p = blockIdx.x * 16 + pl;          // p = b*256 + t
    int b = p >> 8, t = p & 255;
    int len = lens[b];
    int tr = t < len ? len - 1 - t : t;    // bwd un-reversal (packed semantics)
    const float4* hf = (const float4*)(hex + ((size_t)(b >> 3) * T_ + t) * 2048 + (b & 7) * 256);
    const float4* hb = (const float4*)(hex + ((size_t)(4 + (b >> 3)) * T_ + tr) * 2048 + (b & 7) * 256);
    const float4* w0 = (const float4*)(Wout + (size_t)k * 512);
    const float4* w1 = (const float4*)(Wout + (size_t)k * 512 + 256);
    float acc = bout[k];
#pragma unroll 4
    for (int j = 0; j < 64; ++j) {
        float4 h4 = hf[j], v4 = w0[j];
        acc += h4.x * v4.x + h4.y * v4.y + h4.z * v4.z + h4.w * v4.w;
    }
#pragma unroll 4
    for (int j = 0; j < 64; ++j) {
        float4 h4 = hb[j], v4 = w1[j];
        acc += h4.x * v4.x + h4.y * v4.y + h4.z * v4.z + h4.w * v4.w;
    }
    feats[(size_t)p * K_ + k] = acc;
}

// ---------- Viterbi + backtrace: single block, feats prefetch, bp nibble-packed ----------
__global__ __launch_bounds__(512) void viterbi_k(
    const float* __restrict__ feats, const float* __restrict__ trans,
    const int* __restrict__ lens, float* __restrict__ out) {
    __shared__ float fv[2][B_][16];
    __shared__ float tl[K_][16];
    __shared__ unsigned char bp[T_][B_][6];    // 4-bit backpointers, 48KB
    __shared__ int best_last[B_];
    int tid = threadIdx.x;
    int b = tid >> 4, lane = tid & 15;
    if (tid < K_ * K_) tl[tid / 12][tid % 12] = trans[tid];
    if (lane < K_) fv[0][b][lane] = (lane == START_) ? 0.f : NEG_;
    __syncthreads();
    int len = lens[b];
    int pp = 0;
    float f_cur = 0.f;
    if (lane < K_) f_cur = feats[(size_t)b * T_ * K_ + lane];
    for (int t = 0; t < T_; ++t) {
        float f_nxt = 0.f;                       // prefetch t+1 before the compute chain
        if (t + 1 < T_ && lane < K_) f_nxt = feats[((size_t)b * T_ + t + 1) * K_ + lane];
        if (lane < K_) {
            float best = fv[pp][b][0] + tl[lane][0];
            int argp = 0;
#pragma unroll
            for (int p = 1; p < K_; ++p) {
                float v = fv[pp][b][p] + tl[lane][p];
                if (v > best) { best = v; argp = p; }   // strict > = first-max (matches jnp.argmax)
            }
            float nb = best + f_cur;
            fv[pp ^ 1][b][lane] = (t < len) ? nb : fv[pp][b][lane];
            int other = __shfl_xor(argp, 1);
            if ((lane & 1) == 0) bp[t][b][lane >> 1] = (unsigned char)(argp | (other << 4));
        }
        __syncthreads();
        pp ^= 1;
        f_cur = f_nxt;
    }
    if (lane == 0) {
        float best = fv[pp][b][0] + tl[STOP_][0];
        int bl = 0;
#pragma unroll
        for (int p = 1; p < K_; ++p) {
            float v = fv[pp][b][p] + tl[STOP_][p];
            if (v > best) { best = v; bl = p; }
        }
        out[b] = best;
        best_last[b] = bl;
    }
    __syncthreads();
    if (lane == 0) {
        int tag = best_last[b];
        for (int t = T_ - 1; t >= 0; --t) {
            int m = (t < len);
            out[B_ + b * T_ + t] = (float)(m ? tag : -1);
            if (m) tag = (bp[t][b][tag >> 1] >> ((tag & 1) * 4)) & 15;
        }
    }
}

extern "C" void kernel_launch(void* const* d_in, const int* in_sizes, int n_in,
                              void* d_out, int out_size, void* d_ws, size_t ws_size,
                              hipStream_t stream) {
    const int*   sent  = (const int*)d_in[0];
    const int*   lens  = (const int*)d_in[1];
    const float* emb   = (const float*)d_in[2];
    const float* Wih_f = (const float*)d_in[3];
    const float* Whh_f = (const float*)d_in[4];
    const float* bih_f = (const float*)d_in[5];
    const float* bhh_f = (const float*)d_in[6];
    const float* Wih_b = (const float*)d_in[7];
    const float* Whh_b = (const float*)d_in[8];
    const float* bih_b = (const float*)d_in[9];
    const float* bhh_b = (const float*)d_in[10];
    const float* h0    = (const float*)d_in[11];
    const float* c0    = (const float*)d_in[12];
    const float* Wout  = (const float*)d_in[13];
    const float* bout  = (const float*)d_in[14];
    const float* trans = (const float*)d_in[15];
    float* out = (float*)d_out;

    char* ws = (char*)d_ws;
    int*   tokA  = (int*)ws;                                  // 64 KB
    float* WhhT  = (float*)(ws + 65536);                      // 2 MB
    float* G     = (float*)(ws + 2162688);                    // 67.1 MB
    float* feats = (float*)(ws + 69271552);                   // 0.39 MB
    float* hex   = (float*)(ws + 69664768);                   // 16 MB  [8 groups][T][2048]

    tok_gather<<<64, 256, 0, stream>>>(sent, lens, tokA);
    whh_tr<<<512, 256, 0, stream>>>(Whh_f, Whh_b, WhhT);
    hex_init<<<4096, 256, 0, stream>>>(hex);
    in_gemm<<<dim3(8, 64, 2), 256, 0, stream>>>(emb, tokA, Wih_f, Wih_b,
                                                bih_f, bhh_f, bih_b, bhh_b, G);
    lstm_rec6<<<64, 512, 0, stream>>>(WhhT, G, h0, c0, lens, hex);
    feat_k<<<512, 192, 0, stream>>>(hex, lens, Wout, bout, feats);
    viterbi_k<<<1, 512, 0, stream>>>(feats, trans, lens, out);
}